// Round 6
// baseline (2008.209 us; speedup 1.0000x reference)
//
#include <hip/hip_runtime.h>

#define NA 100000
#define MN 12
#define KE 41
#define N0C 2500
#define EPSBN 1e-5f
#define ROWDW 24                 // EF dwords per (n,m) row: 48 f16 (k 41..47 zero)
#define CONV_BLOCKS 1536
#define CONV_WAVES (CONV_BLOCKS * 4)

typedef _Float16 h2v __attribute__((ext_vector_type(2)));
typedef _Float16 h8v __attribute__((ext_vector_type(8)));
typedef float f4v __attribute__((ext_vector_type(4)));
typedef unsigned int uint;
union H2U { uint u; h2v h; };

__device__ __forceinline__ float softplusf(float x){
  float e = __expf(-fabsf(x));
  return fmaxf(x, 0.f) + __logf(1.f + e);
}
__device__ __forceinline__ float sigmoidf(float x){
  return __fdividef(1.f, 1.f + __expf(-x));
}
__device__ __forceinline__ int waveid(){
  return __builtin_amdgcn_readfirstlane((int)((blockIdx.x * blockDim.x + threadIdx.x) >> 6));
}

// ---- e (N,M,41) f32 -> EF [n][m][24 dwords of half2], k 41..47 zero ----
__global__ __launch_bounds__(256) void k_cast_e(const float* __restrict__ e,
                                                uint* __restrict__ EF)
{
  const int TOT = NA * MN * ROWDW;
  for (int i = blockIdx.x * 256 + threadIdx.x; i < TOT; i += gridDim.x * 256) {
    int r = i / ROWDW, k2 = i - r * ROWDW;
    const float* row = e + (size_t)r * KE;
    float a = 0.f, b = 0.f;
    if (k2 < 20) { a = row[2 * k2]; b = row[2 * k2 + 1]; }
    else if (k2 == 20) { a = row[40]; }
    H2U cv; cv.h = h2v{(_Float16)a, (_Float16)b};
    EF[i] = cv.u;
  }
}

// ---- embedding: h = atom_fea @ emb_W + emb_b ----
__global__ __launch_bounds__(256) void k_embed(const float* __restrict__ af,
                                               const float* __restrict__ W,
                                               const float* __restrict__ b,
                                               float* __restrict__ h, int nw)
{
  int t = threadIdx.x & 63;
  int wid = waveid();
  float bias = b[t];
  for (int n0 = wid * 2; n0 < NA; n0 += nw * 2) {
    int n1 = n0 + 1;
    bool has1 = (n1 < NA);
    const float* a0 = af + (size_t)n0 * 92;
    const float* a1 = af + (size_t)(has1 ? n1 : n0) * 92;
    float acc0 = bias, acc1 = bias;
#pragma unroll 4
    for (int k = 0; k < 92; ++k) {
      float w = W[k * 64 + t];
      acc0 += a0[k] * w;
      acc1 += a1[k] * w;
    }
    h[(size_t)n0 * 64 + t] = acc0;
    if (has1) h[(size_t)n1 * 64 + t] = acc1;
  }
}

// ---- k_hw<FUSE>: optionally h = softplus(h + BN2(summed)) first (in regs), then
//      hWs/hWn = pack_f16( h @ [W_self | W_nbr] ) ----
template<int FUSE>
__global__ __launch_bounds__(256) void k_hw(float* __restrict__ h,
                                            const float* __restrict__ summed,
                                            const float* __restrict__ scsh2, // [sc64|sh64]
                                            const float* __restrict__ fcW,   // (169,128)
                                            uint* __restrict__ hWs,
                                            uint* __restrict__ hWn, int nw)
{
  __shared__ float Wl[64 * 256];
  for (int i = threadIdx.x; i < 64 * 256; i += 256) {
    int c = i >> 8, q = i & 255;
    int j = q & 63, part = q >> 6;
    Wl[(c * 64 + j) * 4 + part] = fcW[(c + ((part >> 1) << 6)) * 128 + ((part & 1) << 6) + j];
  }
  __syncthreads();
  int t = threadIdx.x & 63;
  int wid = waveid();
  float sc = 0.f, sh = 0.f;
  if (FUSE) { sc = scsh2[t]; sh = scsh2[64 + t]; }
  const float4* W4 = (const float4*)Wl;
  for (int n0 = wid * 2; n0 < NA; n0 += nw * 2) {
    int n1 = n0 + 1;
    bool has1 = (n1 < NA);
    float hf0 = h[(size_t)n0 * 64 + t];
    float hf1 = h[(size_t)(has1 ? n1 : n0) * 64 + t];
    if (FUSE) {
      hf0 = softplusf(hf0 + summed[(size_t)n0 * 64 + t] * sc + sh);
      hf1 = softplusf(hf1 + summed[(size_t)(has1 ? n1 : n0) * 64 + t] * sc + sh);
      h[(size_t)n0 * 64 + t] = hf0;
      if (has1) h[(size_t)n1 * 64 + t] = hf1;
    }
    float4 A = {0,0,0,0}, B = {0,0,0,0};
#pragma unroll 4
    for (int c = 0; c < 64; ++c) {
      float4 w = W4[c * 64 + t];
      float x0 = __shfl(hf0, c, 64);
      float x1 = __shfl(hf1, c, 64);
      A.x += x0 * w.x; A.y += x0 * w.y; A.z += x0 * w.z; A.w += x0 * w.w;
      B.x += x1 * w.x; B.y += x1 * w.y; B.z += x1 * w.z; B.w += x1 * w.w;
    }
    H2U p0, p1;
    p0.h = h2v{(_Float16)A.x, (_Float16)A.y};
    p1.h = h2v{(_Float16)A.z, (_Float16)A.w};
    hWs[(size_t)n0 * 64 + t] = p0.u;
    hWn[(size_t)n0 * 64 + t] = p1.u;
    if (has1) {
      p0.h = h2v{(_Float16)B.x, (_Float16)B.y};
      p1.h = h2v{(_Float16)B.z, (_Float16)B.w};
      hWs[(size_t)n1 * 64 + t] = p0.u;
      hWn[(size_t)n1 * 64 + t] = p1.u;
    }
  }
}

// ---- conv pass. MODE 0: BN1 stats only. MODE 1: apply+summed (recompute fallback).
//      MODE 2: BN1 stats + write packed-f16 g to g16 (materialize path).
// R3-proven structure: loads AFTER MFMA, low VGPR; 12-row LDS tile.
template<int MODE>
__global__ __launch_bounds__(256) void k_conv(const uint* __restrict__ EF,
                                              const uint* __restrict__ hWs,
                                              const uint* __restrict__ hWn,
                                              const int*  __restrict__ idx,
                                              const float* __restrict__ We,   // fcW rows 128..168
                                              const float* __restrict__ scsh, // [sc128|sh128]
                                              float* __restrict__ summed,
                                              float* __restrict__ stats,
                                              uint* __restrict__ g16)
{
  __shared__ float gt_all[4][12 * 132];
  int l = threadIdx.x & 63;
  int w = threadIdx.x >> 6;
  float* gt = gt_all[w];
  int wid = __builtin_amdgcn_readfirstlane(blockIdx.x * 4 + w);
  int c16 = l & 15, kg = l >> 4;

  // preload B fragments: b1 = We k 0..31, b2 = We k 32..47 (lanes kg>=2 zero)
  h8v b1[8], b2[8];
#pragma unroll
  for (int T = 0; T < 8; ++T) {
    h8v v1 = {0,0,0,0,0,0,0,0}, v2 = {0,0,0,0,0,0,0,0};
#pragma unroll
    for (int j = 0; j < 8; ++j)
      v1[j] = (_Float16)We[(kg * 8 + j) * 128 + T * 16 + c16];
    if (kg < 2) {
#pragma unroll
      for (int j = 0; j < 8; ++j) {
        int k = 32 + kg * 8 + j;
        v2[j] = (k < KE) ? (_Float16)We[k * 128 + T * 16 + c16] : (_Float16)0.f;
      }
    }
    b1[T] = v1; b2[T] = v2;
  }

  float sc0 = 0, sh0 = 0, sc1 = 0, sh1 = 0;
  if (MODE == 1) { sc0 = scsh[l]; sc1 = scsh[l + 64]; sh0 = scsh[128 + l]; sh1 = scsh[192 + l]; }
  float s0 = 0, q0 = 0, s1 = 0, q1 = 0;

  for (int n = wid; n < NA; n += CONV_WAVES) {
    const uint* ep = EF + (size_t)n * (MN * ROWDW);
    h8v a1 = {0,0,0,0,0,0,0,0}, a2 = {0,0,0,0,0,0,0,0};
    if (c16 < MN) {
      a1 = *(const h8v*)(ep + c16 * ROWDW + kg * 4);
      if (kg < 2) a2 = *(const h8v*)(ep + c16 * ROWDW + 16 + kg * 4);
    }
    f4v acc[8];
#pragma unroll
    for (int T = 0; T < 8; ++T) acc[T] = f4v{0.f, 0.f, 0.f, 0.f};
#pragma unroll
    for (int T = 0; T < 8; ++T)
      acc[T] = __builtin_amdgcn_mfma_f32_16x16x32_f16(a1, b1[T], acc[T], 0, 0, 0);
#pragma unroll
    for (int T = 0; T < 8; ++T)
      acc[T] = __builtin_amdgcn_mfma_f32_16x16x32_f16(a2, b2[T], acc[T], 0, 0, 0);

    // stage rows 0..11: row = kg*4+r (kg<3), col = T*16+c16 (2-way max, free)
    if (kg < 3) {
#pragma unroll
      for (int T = 0; T < 8; ++T)
#pragma unroll
        for (int r = 0; r < 4; ++r)
          gt[(kg * 4 + r) * 132 + T * 16 + c16] = acc[T][r];
    }

    // epilogue (R3 ordering: loads here, after MFMA)
    const int* ip = idx + n * MN;                      // n wave-uniform -> s_load
    H2U sp; sp.u = hWs[(size_t)n * 64 + l];
    float self0 = (float)sp.h[0], self1 = (float)sp.h[1];
    uint nbp[MN];
#pragma unroll
    for (int m = 0; m < MN; ++m) nbp[m] = hWn[(size_t)ip[m] * 64 + l];
    float accsum = 0.f;
#pragma unroll
    for (int m = 0; m < MN; ++m) {
      H2U nv; nv.u = nbp[m];
      float g0 = gt[m * 132 + l]      + self0 + (float)nv.h[0];
      float g1 = gt[m * 132 + 64 + l] + self1 + (float)nv.h[1];
      if (MODE == 1) {
        float f  = sigmoidf(g0 * sc0 + sh0);
        float cr = softplusf(g1 * sc1 + sh1);
        accsum += f * cr;
      } else {
        s0 += g0; q0 += g0 * g0;
        s1 += g1; q1 += g1 * g1;
        if (MODE == 2) {
          H2U pk; pk.h = h2v{(_Float16)g0, (_Float16)g1};
          g16[((size_t)n * MN + m) * 64 + l] = pk.u;
        }
      }
    }
    if (MODE == 1) {
      summed[(size_t)n * 64 + l] = accsum;
      s0 += accsum; q0 += accsum * accsum;             // BN2 stats
    }
  }
  if (MODE == 1) {
    atomicAdd(&stats[l], s0);
    atomicAdd(&stats[64 + l], q0);
  } else {
    atomicAdd(&stats[l], s0);
    atomicAdd(&stats[64 + l], s1);
    atomicAdd(&stats[128 + l], q0);
    atomicAdd(&stats[192 + l], q1);
  }
}

// ---- streaming gate: read g16, apply BN1+sigmoid*softplus, m-sum, BN2 stats ----
__global__ __launch_bounds__(256) void k_gate(const uint* __restrict__ g16,
                                              const float* __restrict__ scsh, // [sc128|sh128]
                                              float* __restrict__ summed,
                                              float* __restrict__ stats, int nw)
{
  int l = threadIdx.x & 63;
  int wid = waveid();
  float sc0 = scsh[l], sc1 = scsh[l + 64];
  float sh0 = scsh[128 + l], sh1 = scsh[192 + l];
  float bs = 0.f, bq = 0.f;
  for (int n = wid; n < NA; n += nw) {
    const uint* gp = g16 + (size_t)n * MN * 64 + l;
    uint u[MN];
#pragma unroll
    for (int m = 0; m < MN; ++m) u[m] = gp[m * 64];   // all 12 loads in flight
    float accsum = 0.f;
#pragma unroll
    for (int m = 0; m < MN; ++m) {
      H2U gv; gv.u = u[m];
      float f  = sigmoidf((float)gv.h[0] * sc0 + sh0);
      float cr = softplusf((float)gv.h[1] * sc1 + sh1);
      accsum += f * cr;
    }
    summed[(size_t)n * 64 + l] = accsum;
    bs += accsum; bq += accsum * accsum;
  }
  atomicAdd(&stats[l], bs);
  atomicAdd(&stats[64 + l], bq);
}

// ---- BN finalize ----
__global__ void k_fin1(const float* __restrict__ st, const float* __restrict__ g,
                       const float* __restrict__ b, float* __restrict__ scsh)
{
  int j = threadIdx.x;                 // 128
  float inv = 1.f / (float)(NA * MN);
  float mean = st[j] * inv;
  float var  = st[128 + j] * inv - mean * mean;
  float rstd = rsqrtf(var + EPSBN);
  float sc = g[j] * rstd;
  scsh[j] = sc;
  scsh[128 + j] = b[j] - mean * sc;
}
__global__ void k_fin2(const float* __restrict__ st, const float* __restrict__ g,
                       const float* __restrict__ b, float* __restrict__ scsh)
{
  int j = threadIdx.x;                 // 64
  float inv = 1.f / (float)NA;
  float mean = st[j] * inv;
  float var  = st[64 + j] * inv - mean * mean;
  float rstd = rsqrtf(var + EPSBN);
  float sc = g[j] * rstd;
  scsh[j] = sc;
  scsh[64 + j] = b[j] - mean * sc;
}

// ---- h = softplus(h + BN2(summed)) (after last layer) ----
__global__ __launch_bounds__(256) void k_bn2res(float* __restrict__ h,
                                                const float* __restrict__ summed,
                                                const float* __restrict__ scsh)
{
  int tot = NA * 64 / 4;
  const float4* s4 = (const float4*)summed;
  float4* h4 = (float4*)h;
  for (int i = blockIdx.x * blockDim.x + threadIdx.x; i < tot; i += gridDim.x * blockDim.x) {
    int c4 = i & 15;
    float4 sc = ((const float4*)scsh)[c4];
    float4 sh = ((const float4*)(scsh + 64))[c4];
    float4 hv = h4[i], sv = s4[i];
    hv.x = softplusf(hv.x + sv.x * sc.x + sh.x);
    hv.y = softplusf(hv.y + sv.y * sc.y + sh.y);
    hv.z = softplusf(hv.z + sv.z * sc.z + sh.z);
    hv.w = softplusf(hv.w + sv.w * sc.w + sh.w);
    h4[i] = hv;
  }
}

// ---- segment-sum pool (crystal_atom_idx sorted) ----
__global__ __launch_bounds__(256) void k_pool(const float* __restrict__ h,
                                              const int* __restrict__ cidx,
                                              float* __restrict__ csum,
                                              float* __restrict__ ccnt, int nw)
{
  int t = threadIdx.x & 63;
  int wid = waveid();
  int chunk = (NA + nw - 1) / nw;
  int n0 = wid * chunk;
  int n1 = min(n0 + chunk, NA);
  if (n0 >= NA) return;
  float acc = 0.f, cacc = 0.f;
  int cur = -1;
  for (int n = n0; n < n1; ++n) {
    int ci = cidx[n];
    if (ci != cur) {
      if (cur >= 0) {
        atomicAdd(&csum[(size_t)cur * 64 + t], acc);
        if (t == 0) atomicAdd(&ccnt[cur], cacc);
      }
      cur = ci; acc = 0.f; cacc = 0.f;
    }
    acc += h[(size_t)n * 64 + t];
    cacc += 1.f;
  }
  if (cur >= 0) {
    atomicAdd(&csum[(size_t)cur * 64 + t], acc);
    if (t == 0) atomicAdd(&ccnt[cur], cacc);
  }
}

// ---- head ----
__global__ __launch_bounds__(256) void k_head(const float* __restrict__ csum,
                                              const float* __restrict__ ccnt,
                                              const float* __restrict__ Wh,   // (64,128)
                                              const float* __restrict__ bh,
                                              const float* __restrict__ Wo,   // (128,1)
                                              const float* __restrict__ bo,
                                              float* __restrict__ out)
{
  __shared__ float Wl[64 * 128];
  for (int i = threadIdx.x; i < 64 * 128; i += 256) Wl[i] = Wh[i];
  __syncthreads();
  int t = threadIdx.x & 63;
  int ci = blockIdx.x * 4 + (threadIdx.x >> 6);
  if (ci >= N0C) return;
  float cnt = fmaxf(ccnt[ci], 1.f);
  float x = softplusf(csum[(size_t)ci * 64 + t] / cnt);
  float acc0 = 0.f, acc1 = 0.f;
#pragma unroll 4
  for (int c = 0; c < 64; ++c) {
    float xc = __shfl(x, c, 64);
    acc0 += xc * Wl[c * 128 + t];
    acc1 += xc * Wl[c * 128 + 64 + t];
  }
  float z0 = softplusf(acc0 + bh[t]);
  float z1 = softplusf(acc1 + bh[64 + t]);
  float part = z0 * Wo[t] + z1 * Wo[64 + t];
#pragma unroll
  for (int s = 32; s >= 1; s >>= 1) part += __shfl_xor(part, s, 64);
  if (t == 0) out[ci] = part + bo[0];
}

extern "C" void kernel_launch(void* const* d_in, const int* in_sizes, int n_in,
                              void* d_out, int out_size, void* d_ws, size_t ws_size,
                              hipStream_t stream)
{
  const float* af    = (const float*)d_in[0];
  const float* nbr   = (const float*)d_in[1];
  const int*   nidx  = (const int*)d_in[2];
  const int*   cidx  = (const int*)d_in[3];
  const float* embW  = (const float*)d_in[4];
  const float* embB  = (const float*)d_in[5];
  const float* fcW   = (const float*)d_in[6];
  // d_in[7] = fc_b: cancelled by BatchNorm mean subtraction
  const float* bn1g  = (const float*)d_in[8];
  const float* bn1b  = (const float*)d_in[9];
  const float* bn2g  = (const float*)d_in[10];
  const float* bn2b  = (const float*)d_in[11];
  const float* headW = (const float*)d_in[12];
  const float* headB = (const float*)d_in[13];
  const float* outW  = (const float*)d_in[14];
  const float* outB  = (const float*)d_in[15];
  float* out = (float*)d_out;

  float* ws = (float*)d_ws;
  size_t off = 0;
  float* h      = ws + off; off += (size_t)NA * 64;
  uint*  hWs    = (uint*)(ws + off); off += (size_t)NA * 64;
  uint*  hWn    = (uint*)(ws + off); off += (size_t)NA * 64;
  uint*  EF     = (uint*)(ws + off); off += (size_t)NA * MN * ROWDW;
  float* summed = ws + off; off += (size_t)NA * 64;
  float* zr     = ws + off;
  float* stats1 = zr;                       // 3*256
  float* stats2 = stats1 + 3 * 256;         // 3*128
  float* csum   = stats2 + 3 * 128;         // 2500*64
  float* ccnt   = csum + (size_t)N0C * 64;  // 2500
  size_t zcount = 3 * 256 + 3 * 128 + (size_t)N0C * 64 + N0C;
  float* scsh1  = ccnt + N0C;               // 3*256
  float* scsh2  = scsh1 + 3 * 256;          // 3*128
  off += zcount + 3 * 256 + 3 * 128;
  uint* g16 = (uint*)(ws + off);            // 307.2 MB, optional
  size_t need_g = (off + (size_t)NA * MN * 64) * sizeof(float);
  bool use_g = (ws_size >= need_g);

  hipMemsetAsync(zr, 0, zcount * sizeof(float), stream);

  k_cast_e<<<4096, 256, 0, stream>>>(nbr, EF);
  k_embed<<<512, 256, 0, stream>>>(af, embW, embB, h, 2048);

  for (int l = 0; l < 3; ++l) {
    const float* Wl = fcW + (size_t)l * 169 * 128;
    const float* We = Wl + 128 * 128;
    if (l == 0)
      k_hw<0><<<512, 256, 0, stream>>>(h, nullptr, nullptr, Wl, hWs, hWn, 2048);
    else
      k_hw<1><<<512, 256, 0, stream>>>(h, summed, scsh2 + (l - 1) * 128, Wl, hWs, hWn, 2048);
    if (use_g) {
      k_conv<2><<<CONV_BLOCKS, 256, 0, stream>>>(EF, hWs, hWn, nidx, We, nullptr,
                                                 nullptr, stats1 + l * 256, g16);
      k_fin1<<<1, 128, 0, stream>>>(stats1 + l * 256, bn1g + l * 128, bn1b + l * 128,
                                    scsh1 + l * 256);
      k_gate<<<2048, 256, 0, stream>>>(g16, scsh1 + l * 256, summed,
                                       stats2 + l * 128, 8192);
    } else {
      k_conv<0><<<CONV_BLOCKS, 256, 0, stream>>>(EF, hWs, hWn, nidx, We, nullptr,
                                                 nullptr, stats1 + l * 256, nullptr);
      k_fin1<<<1, 128, 0, stream>>>(stats1 + l * 256, bn1g + l * 128, bn1b + l * 128,
                                    scsh1 + l * 256);
      k_conv<1><<<CONV_BLOCKS, 256, 0, stream>>>(EF, hWs, hWn, nidx, We, scsh1 + l * 256,
                                                 summed, stats2 + l * 128, nullptr);
    }
    k_fin2<<<1, 64, 0, stream>>>(stats2 + l * 128, bn2g + l * 64, bn2b + l * 64,
                                 scsh2 + l * 128);
  }

  k_bn2res<<<2048, 256, 0, stream>>>(h, summed, scsh2 + 2 * 128);
  k_pool<<<512, 256, 0, stream>>>(h, cidx, csum, ccnt, 2048);
  k_head<<<625, 256, 0, stream>>>(csum, ccnt, headW, headB, outW, outB, out);
}

// Round 8
// 1725.638 us; speedup vs baseline: 1.1637x; 1.1637x over previous
//
#include <hip/hip_runtime.h>

#define NA 100000
#define MN 12
#define KE 41
#define N0C 2500
#define EPSBN 1e-5f
#define ROWDW 24                 // EF dwords per (n,m) row: 48 f16 (k 41..47 zero)
#define CONV_BLOCKS 1280         // 5 blocks/CU at 31104 B LDS
#define CONV_WAVES (CONV_BLOCKS * 4)
#define WEP 72                   // WeT padded row length in f16 (144 B: 16B-aligned, 2-way banks)
#define GTP 66                   // g-tile padded row length in dwords

typedef _Float16 h2v __attribute__((ext_vector_type(2)));
typedef _Float16 h8v __attribute__((ext_vector_type(8)));
typedef __fp16 fp16x2 __attribute__((ext_vector_type(2)));
typedef float f4v __attribute__((ext_vector_type(4)));
typedef unsigned int uint;
union H2U { uint u; h2v h; fp16x2 p; };

__device__ __forceinline__ float softplusf(float x){
  float e = __expf(-fabsf(x));
  return fmaxf(x, 0.f) + __logf(1.f + e);
}
__device__ __forceinline__ float sigmoidf(float x){
  return __fdividef(1.f, 1.f + __expf(-x));
}
__device__ __forceinline__ int waveid(){
  return __builtin_amdgcn_readfirstlane((int)((blockIdx.x * blockDim.x + threadIdx.x) >> 6));
}

// ---- e (N,M,41) f32 -> EF [n][m][24 dwords of half2], k 41..47 zero ----
__global__ __launch_bounds__(256) void k_cast_e(const float* __restrict__ e,
                                                uint* __restrict__ EF)
{
  const int TOT = NA * MN * ROWDW;
  for (int i = blockIdx.x * 256 + threadIdx.x; i < TOT; i += gridDim.x * 256) {
    int r = i / ROWDW, k2 = i - r * ROWDW;
    const float* row = e + (size_t)r * KE;
    float a = 0.f, b = 0.f;
    if (k2 < 20) { a = row[2 * k2]; b = row[2 * k2 + 1]; }
    else if (k2 == 20) { a = row[40]; }
    H2U cv; cv.h = h2v{(_Float16)a, (_Float16)b};
    EF[i] = cv.u;
  }
}

// ---- embedding: h = atom_fea @ emb_W + emb_b ----
__global__ __launch_bounds__(256) void k_embed(const float* __restrict__ af,
                                               const float* __restrict__ W,
                                               const float* __restrict__ b,
                                               float* __restrict__ h, int nw)
{
  int t = threadIdx.x & 63;
  int wid = waveid();
  float bias = b[t];
  for (int n0 = wid * 2; n0 < NA; n0 += nw * 2) {
    int n1 = n0 + 1;
    bool has1 = (n1 < NA);
    const float* a0 = af + (size_t)n0 * 92;
    const float* a1 = af + (size_t)(has1 ? n1 : n0) * 92;
    float acc0 = bias, acc1 = bias;
#pragma unroll 4
    for (int k = 0; k < 92; ++k) {
      float w = W[k * 64 + t];
      acc0 += a0[k] * w;
      acc1 += a1[k] * w;
    }
    h[(size_t)n0 * 64 + t] = acc0;
    if (has1) h[(size_t)n1 * 64 + t] = acc1;
  }
}

// ---- k_hw<FUSE>: optionally h = softplus(h + BN2(summed)) first (in regs), then
//      hWs/hWn = pack_f16( h @ [W_self | W_nbr] ) ----
template<int FUSE>
__global__ __launch_bounds__(256) void k_hw(float* __restrict__ h,
                                            const float* __restrict__ summed,
                                            const float* __restrict__ scsh2, // [sc64|sh64]
                                            const float* __restrict__ fcW,   // (169,128)
                                            uint* __restrict__ hWs,
                                            uint* __restrict__ hWn, int nw)
{
  __shared__ float Wl[64 * 256];
  for (int i = threadIdx.x; i < 64 * 256; i += 256) {
    int c = i >> 8, q = i & 255;
    int j = q & 63, part = q >> 6;
    Wl[(c * 64 + j) * 4 + part] = fcW[(c + ((part >> 1) << 6)) * 128 + ((part & 1) << 6) + j];
  }
  __syncthreads();
  int t = threadIdx.x & 63;
  int wid = waveid();
  float sc = 0.f, sh = 0.f;
  if (FUSE) { sc = scsh2[t]; sh = scsh2[64 + t]; }
  const float4* W4 = (const float4*)Wl;
  for (int n0 = wid * 2; n0 < NA; n0 += nw * 2) {
    int n1 = n0 + 1;
    bool has1 = (n1 < NA);
    float hf0 = h[(size_t)n0 * 64 + t];
    float hf1 = h[(size_t)(has1 ? n1 : n0) * 64 + t];
    if (FUSE) {
      hf0 = softplusf(hf0 + summed[(size_t)n0 * 64 + t] * sc + sh);
      hf1 = softplusf(hf1 + summed[(size_t)(has1 ? n1 : n0) * 64 + t] * sc + sh);
      h[(size_t)n0 * 64 + t] = hf0;
      if (has1) h[(size_t)n1 * 64 + t] = hf1;
    }
    float4 A = {0,0,0,0}, B = {0,0,0,0};
#pragma unroll 4
    for (int c = 0; c < 64; ++c) {
      float4 w = W4[c * 64 + t];
      float x0 = __shfl(hf0, c, 64);
      float x1 = __shfl(hf1, c, 64);
      A.x += x0 * w.x; A.y += x0 * w.y; A.z += x0 * w.z; A.w += x0 * w.w;
      B.x += x1 * w.x; B.y += x1 * w.y; B.z += x1 * w.z; B.w += x1 * w.w;
    }
    H2U p0, p1;
    p0.h = h2v{(_Float16)A.x, (_Float16)A.y};
    p1.h = h2v{(_Float16)A.z, (_Float16)A.w};
    hWs[(size_t)n0 * 64 + t] = p0.u;
    hWn[(size_t)n0 * 64 + t] = p1.u;
    if (has1) {
      p0.h = h2v{(_Float16)B.x, (_Float16)B.y};
      p1.h = h2v{(_Float16)B.z, (_Float16)B.w};
      hWs[(size_t)n1 * 64 + t] = p0.u;
      hWn[(size_t)n1 * 64 + t] = p1.u;
    }
  }
}

// ---- conv pass. MODE 0: BN1 stats. MODE 1: apply + summed + BN2 stats.
// B-fragments served from LDS (WeT transposed, zero-padded) instead of 64 VGPRs ->
// no per-atom L1 reload of We. g staged to LDS as packed f16 pairs.
template<int MODE>
__global__ __launch_bounds__(256) void k_conv(const uint* __restrict__ EF,
                                              const uint* __restrict__ hWs,
                                              const uint* __restrict__ hWn,
                                              const int*  __restrict__ idx,
                                              const float* __restrict__ We,   // fcW rows 128..168
                                              const float* __restrict__ scsh, // [sc128|sh128]
                                              float* __restrict__ summed,
                                              float* __restrict__ stats)
{
  __shared__ _Float16 WeT[128 * WEP];       // [col][k], k 0..40 real, rest 0  (18.4 KB)
  __shared__ uint gt_all[4][12 * GTP];      // packed (g_j, g_{j+64}) f16 pairs (12.7 KB)
  int tid = threadIdx.x;
  // stage WeT (zero-padded to WEP)
  for (int i = tid; i < 128 * (WEP / 2); i += 256) {
    int col = i / (WEP / 2), k2 = i - col * (WEP / 2);
    int k0 = 2 * k2, k1 = 2 * k2 + 1;
    float a = (k0 < KE) ? We[k0 * 128 + col] : 0.f;
    float b = (k1 < KE) ? We[k1 * 128 + col] : 0.f;
    H2U pk; pk.h = h2v{(_Float16)a, (_Float16)b};
    *(uint*)&WeT[col * WEP + 2 * k2] = pk.u;
  }
  __syncthreads();

  int l = tid & 63;
  int w = tid >> 6;
  uint* gt = gt_all[w];
  int wid = __builtin_amdgcn_readfirstlane(blockIdx.x * 4 + w);
  int c16 = l & 15, kg = l >> 4;

  float sc0 = 0, sh0 = 0, sc1 = 0, sh1 = 0;
  if (MODE == 1) { sc0 = scsh[l]; sc1 = scsh[l + 64]; sh0 = scsh[128 + l]; sh1 = scsh[192 + l]; }
  float s0 = 0, q0 = 0, s1 = 0, q1 = 0;

  for (int n = wid; n < NA; n += CONV_WAVES) {
    const uint* ep = EF + (size_t)n * (MN * ROWDW);
    h8v a1 = {0,0,0,0,0,0,0,0}, a2 = {0,0,0,0,0,0,0,0};
    if (c16 < MN) {
      a1 = *(const h8v*)(ep + c16 * ROWDW + kg * 4);
      if (kg < 2) a2 = *(const h8v*)(ep + c16 * ROWDW + 16 + kg * 4);
    }
    f4v acc[8];
#pragma unroll
    for (int T = 0; T < 8; ++T) acc[T] = f4v{0.f, 0.f, 0.f, 0.f};
#pragma unroll
    for (int T = 0; T < 8; ++T) {
      h8v b = *(const h8v*)&WeT[(T * 16 + c16) * WEP + kg * 8];        // k = kg*8..+7
      acc[T] = __builtin_amdgcn_mfma_f32_16x16x32_f16(a1, b, acc[T], 0, 0, 0);
    }
#pragma unroll
    for (int T = 0; T < 8; ++T) {
      h8v b = *(const h8v*)&WeT[(T * 16 + c16) * WEP + 32 + kg * 8];   // k = 32+kg*8 (0-pad >=41)
      acc[T] = __builtin_amdgcn_mfma_f32_16x16x32_f16(a2, b, acc[T], 0, 0, 0);
    }

    // stage rows 0..11 as packed f16 pairs: pair col j = T*16+c16 (T<4), rows kg*4+r
    if (kg < 3) {
#pragma unroll
      for (int T = 0; T < 4; ++T)
#pragma unroll
        for (int r = 0; r < 4; ++r) {
          H2U u; u.p = __builtin_amdgcn_cvt_pkrtz(acc[T][r], acc[T + 4][r]);
          gt[(kg * 4 + r) * GTP + T * 16 + c16] = u.u;
        }
    }

    // epilogue: lane l owns cols {l, l+64}
    const int* ip = idx + n * MN;                      // wave-uniform -> s_load
    H2U sp; sp.u = hWs[(size_t)n * 64 + l];
    float self0 = (float)sp.h[0], self1 = (float)sp.h[1];
    uint nbp[MN];
#pragma unroll
    for (int m = 0; m < MN; ++m) nbp[m] = hWn[(size_t)ip[m] * 64 + l];
    float accsum = 0.f;
#pragma unroll
    for (int m = 0; m < MN; ++m) {
      H2U nv; nv.u = nbp[m];
      H2U gv; gv.u = gt[m * GTP + l];
      float g0 = (float)gv.h[0] + self0 + (float)nv.h[0];
      float g1 = (float)gv.h[1] + self1 + (float)nv.h[1];
      if (MODE == 1) {
        float f  = sigmoidf(g0 * sc0 + sh0);
        float cr = softplusf(g1 * sc1 + sh1);
        accsum += f * cr;
      } else {
        s0 += g0; q0 += g0 * g0;
        s1 += g1; q1 += g1 * g1;
      }
    }
    if (MODE == 1) {
      summed[(size_t)n * 64 + l] = accsum;
      s0 += accsum; q0 += accsum * accsum;             // BN2 stats
    }
  }
  if (MODE == 1) {
    atomicAdd(&stats[l], s0);
    atomicAdd(&stats[64 + l], q0);
  } else {
    atomicAdd(&stats[l], s0);
    atomicAdd(&stats[64 + l], s1);
    atomicAdd(&stats[128 + l], q0);
    atomicAdd(&stats[192 + l], q1);
  }
}

// ---- BN finalize ----
__global__ void k_fin1(const float* __restrict__ st, const float* __restrict__ g,
                       const float* __restrict__ b, float* __restrict__ scsh)
{
  int j = threadIdx.x;                 // 128
  float inv = 1.f / (float)(NA * MN);
  float mean = st[j] * inv;
  float var  = st[128 + j] * inv - mean * mean;
  float rstd = rsqrtf(var + EPSBN);
  float sc = g[j] * rstd;
  scsh[j] = sc;
  scsh[128 + j] = b[j] - mean * sc;
}
__global__ void k_fin2(const float* __restrict__ st, const float* __restrict__ g,
                       const float* __restrict__ b, float* __restrict__ scsh)
{
  int j = threadIdx.x;                 // 64
  float inv = 1.f / (float)NA;
  float mean = st[j] * inv;
  float var  = st[64 + j] * inv - mean * mean;
  float rstd = rsqrtf(var + EPSBN);
  float sc = g[j] * rstd;
  scsh[j] = sc;
  scsh[64 + j] = b[j] - mean * sc;
}

// ---- h = softplus(h + BN2(summed)) (after last layer) ----
__global__ __launch_bounds__(256) void k_bn2res(float* __restrict__ h,
                                                const float* __restrict__ summed,
                                                const float* __restrict__ scsh)
{
  int tot = NA * 64 / 4;
  const float4* s4 = (const float4*)summed;
  float4* h4 = (float4*)h;
  for (int i = blockIdx.x * blockDim.x + threadIdx.x; i < tot; i += gridDim.x * blockDim.x) {
    int c4 = i & 15;
    float4 sc = ((const float4*)scsh)[c4];
    float4 sh = ((const float4*)(scsh + 64))[c4];
    float4 hv = h4[i], sv = s4[i];
    hv.x = softplusf(hv.x + sv.x * sc.x + sh.x);
    hv.y = softplusf(hv.y + sv.y * sc.y + sh.y);
    hv.z = softplusf(hv.z + sv.z * sc.z + sh.z);
    hv.w = softplusf(hv.w + sv.w * sc.w + sh.w);
    h4[i] = hv;
  }
}

// ---- segment-sum pool (crystal_atom_idx sorted) ----
__global__ __launch_bounds__(256) void k_pool(const float* __restrict__ h,
                                              const int* __restrict__ cidx,
                                              float* __restrict__ csum,
                                              float* __restrict__ ccnt, int nw)
{
  int t = threadIdx.x & 63;
  int wid = waveid();
  int chunk = (NA + nw - 1) / nw;
  int n0 = wid * chunk;
  int n1 = min(n0 + chunk, NA);
  if (n0 >= NA) return;
  float acc = 0.f, cacc = 0.f;
  int cur = -1;
  for (int n = n0; n < n1; ++n) {
    int ci = cidx[n];
    if (ci != cur) {
      if (cur >= 0) {
        atomicAdd(&csum[(size_t)cur * 64 + t], acc);
        if (t == 0) atomicAdd(&ccnt[cur], cacc);
      }
      cur = ci; acc = 0.f; cacc = 0.f;
    }
    acc += h[(size_t)n * 64 + t];
    cacc += 1.f;
  }
  if (cur >= 0) {
    atomicAdd(&csum[(size_t)cur * 64 + t], acc);
    if (t == 0) atomicAdd(&ccnt[cur], cacc);
  }
}

// ---- head ----
__global__ __launch_bounds__(256) void k_head(const float* __restrict__ csum,
                                              const float* __restrict__ ccnt,
                                              const float* __restrict__ Wh,   // (64,128)
                                              const float* __restrict__ bh,
                                              const float* __restrict__ Wo,   // (128,1)
                                              const float* __restrict__ bo,
                                              float* __restrict__ out)
{
  __shared__ float Wl[64 * 128];
  for (int i = threadIdx.x; i < 64 * 128; i += 256) Wl[i] = Wh[i];
  __syncthreads();
  int t = threadIdx.x & 63;
  int ci = blockIdx.x * 4 + (threadIdx.x >> 6);
  if (ci >= N0C) return;
  float cnt = fmaxf(ccnt[ci], 1.f);
  float x = softplusf(csum[(size_t)ci * 64 + t] / cnt);
  float acc0 = 0.f, acc1 = 0.f;
#pragma unroll 4
  for (int c = 0; c < 64; ++c) {
    float xc = __shfl(x, c, 64);
    acc0 += xc * Wl[c * 128 + t];
    acc1 += xc * Wl[c * 128 + 64 + t];
  }
  float z0 = softplusf(acc0 + bh[t]);
  float z1 = softplusf(acc1 + bh[64 + t]);
  float part = z0 * Wo[t] + z1 * Wo[64 + t];
#pragma unroll
  for (int s = 32; s >= 1; s >>= 1) part += __shfl_xor(part, s, 64);
  if (t == 0) out[ci] = part + bo[0];
}

extern "C" void kernel_launch(void* const* d_in, const int* in_sizes, int n_in,
                              void* d_out, int out_size, void* d_ws, size_t ws_size,
                              hipStream_t stream)
{
  const float* af    = (const float*)d_in[0];
  const float* nbr   = (const float*)d_in[1];
  const int*   nidx  = (const int*)d_in[2];
  const int*   cidx  = (const int*)d_in[3];
  const float* embW  = (const float*)d_in[4];
  const float* embB  = (const float*)d_in[5];
  const float* fcW   = (const float*)d_in[6];
  // d_in[7] = fc_b: cancelled by BatchNorm mean subtraction
  const float* bn1g  = (const float*)d_in[8];
  const float* bn1b  = (const float*)d_in[9];
  const float* bn2g  = (const float*)d_in[10];
  const float* bn2b  = (const float*)d_in[11];
  const float* headW = (const float*)d_in[12];
  const float* headB = (const float*)d_in[13];
  const float* outW  = (const float*)d_in[14];
  const float* outB  = (const float*)d_in[15];
  float* out = (float*)d_out;

  float* ws = (float*)d_ws;
  size_t off = 0;
  float* h      = ws + off; off += (size_t)NA * 64;
  uint*  hWs    = (uint*)(ws + off); off += (size_t)NA * 64;
  uint*  hWn    = (uint*)(ws + off); off += (size_t)NA * 64;
  uint*  EF     = (uint*)(ws + off); off += (size_t)NA * MN * ROWDW;
  float* summed = ws + off; off += (size_t)NA * 64;
  float* zr     = ws + off;
  float* stats1 = zr;                       // 3*256
  float* stats2 = stats1 + 3 * 256;         // 3*128
  float* csum   = stats2 + 3 * 128;         // 2500*64
  float* ccnt   = csum + (size_t)N0C * 64;  // 2500
  size_t zcount = 3 * 256 + 3 * 128 + (size_t)N0C * 64 + N0C;
  float* scsh1  = ccnt + N0C;               // 3*256
  float* scsh2  = scsh1 + 3 * 256;          // 3*128

  hipMemsetAsync(zr, 0, zcount * sizeof(float), stream);

  k_cast_e<<<4096, 256, 0, stream>>>(nbr, EF);
  k_embed<<<512, 256, 0, stream>>>(af, embW, embB, h, 2048);

  for (int l = 0; l < 3; ++l) {
    const float* Wl = fcW + (size_t)l * 169 * 128;
    const float* We = Wl + 128 * 128;
    if (l == 0)
      k_hw<0><<<512, 256, 0, stream>>>(h, nullptr, nullptr, Wl, hWs, hWn, 2048);
    else
      k_hw<1><<<512, 256, 0, stream>>>(h, summed, scsh2 + (l - 1) * 128, Wl, hWs, hWn, 2048);
    k_conv<0><<<CONV_BLOCKS, 256, 0, stream>>>(EF, hWs, hWn, nidx, We, nullptr,
                                               nullptr, stats1 + l * 256);
    k_fin1<<<1, 128, 0, stream>>>(stats1 + l * 256, bn1g + l * 128, bn1b + l * 128,
                                  scsh1 + l * 256);
    k_conv<1><<<CONV_BLOCKS, 256, 0, stream>>>(EF, hWs, hWn, nidx, We, scsh1 + l * 256,
                                               summed, stats2 + l * 128);
    k_fin2<<<1, 64, 0, stream>>>(stats2 + l * 128, bn2g + l * 64, bn2b + l * 64,
                                 scsh2 + l * 128);
  }

  k_bn2res<<<2048, 256, 0, stream>>>(h, summed, scsh2 + 2 * 128);
  k_pool<<<512, 256, 0, stream>>>(h, cidx, csum, ccnt, 2048);
  k_head<<<625, 256, 0, stream>>>(csum, ccnt, headW, headB, outW, outB, out);
}